// Round 20
// baseline (86.235 us; speedup 1.0000x reference)
//
#include <hip/hip_runtime.h>
#include <hip/hip_bf16.h>
#include <stdint.h>

typedef __bf16 bf16x8 __attribute__((ext_vector_type(8)));
typedef __bf16 bf16x4 __attribute__((ext_vector_type(4)));
typedef float f32x4 __attribute__((ext_vector_type(4)));

#define N_NODES 32
#define FDIM 256
#define N_TYPES 8
#define BT_TILE 32
#define TILES 16              // A-tiles per block
#define ROW_B (FDIM * 2)      // 512 B per LDS row (bf16)

// XOR swizzle: row stride 512B puts each k-column in one bank; (row&7)<<4
// spreads 16B slots across 8 positions. Applied on write and read.
__device__ __forceinline__ unsigned swz(unsigned byte_off, unsigned row) {
    return byte_off ^ ((row & 7u) << 4);
}
__device__ __forceinline__ void lds_dma16(void* lds, const void* g) {
    __builtin_amdgcn_global_load_lds(
        (const __attribute__((address_space(1))) unsigned int*)g,
        (__attribute__((address_space(3))) unsigned int*)lds, 16, 0, 0);
}

// ---------------------------------------------------------------------------
// k0: one-time W fp32->bf16, PRE-SWIZZLED full [256 o x 256 k] image per type
// so k1 stages it with linear global_load_lds. Image byte
// L = (o*512 + k*2) ^ ((o&7)<<4) holds W[t][o][k].  (~3us)
// ---------------------------------------------------------------------------
__global__ __launch_bounds__(256) void k0_convert_w(
    const float* __restrict__ w, __bf16* __restrict__ wp)
{
    int idx = blockIdx.x * 256 + threadIdx.x;   // [t][o][k]
    int t = idx >> 16, o = (idx >> 8) & 255, k = idx & 255;
    unsigned L = (unsigned)(o * ROW_B + k * 2) ^ ((o & 7u) << 4);
    wp[(size_t)t * (FDIM * FDIM) + (L >> 1)] = (__bf16)w[idx];
}

// ---------------------------------------------------------------------------
// k1: persistent-W GEMM (FROZEN, ~30us = at this structure's BW ceiling).
// Block = (n, bt-group of 512 rows). Full W[t] bf16 resident in LDS (128 KB,
// DMA'd once); 16 A-tiles [32 x 256], A double-buffered + reg-prefetched one
// tile ahead; XOR-swizzled LDS; bf16 MFMA 16x16x32, fp32 accum; bias in
// epilogue. Writes out1 bf16 into the FIRST 16 KB of each out[bt] 32KB slot,
// MFMA-frag-permuted: element (bt, n, p), p = wid*64 + lr*4 + nf, at byte
// bt*32768 + n*512 + p*2; 8B/lane contiguous stores.
// Lessons: bf16 epilogue only (fp32 epilogues = 76-94us); never row-major
// scatter (R6: 1.76 TB/s).
// ---------------------------------------------------------------------------
__global__ __launch_bounds__(256, 1) void k1_node_gemm(
    const float* __restrict__ input, const __bf16* __restrict__ wp,
    const float* __restrict__ bias, const int* __restrict__ ntype,
    char* __restrict__ outb)
{
    __shared__ __bf16 sW[FDIM * FDIM];          // 131072 B
    __shared__ __bf16 sA[2][BT_TILE * FDIM];    // 2 x 16384 B  (total = 160 KiB)

    const int tid = threadIdx.x;
    const int n = blockIdx.x >> 3;
    const int base = (blockIdx.x & 7) * (TILES * BT_TILE);
    const int t = ntype[n];

    const int wid = tid >> 6, lane = tid & 63;
    const int lr = lane & 15, lq = lane >> 4;
    const int sr = tid >> 3;        // staging row 0..31
    const int sk = tid & 7;         // staging k-octet

    char* sWb = (char*)sW;
    char* sA0 = (char*)sA[0];
    char* sA1 = (char*)sA[1];

    // ---- prologue ----
    const char* wsrc = (const char*)(wp + (size_t)t * (FDIM * FDIM));
#pragma unroll
    for (int j = 0; j < 32; ++j)
        lds_dma16(sWb + j * 4096 + tid * 16, wsrc + j * 4096 + tid * 16);

    float bv[4];
#pragma unroll
    for (int nf = 0; nf < 4; ++nf)
        bv[nf] = bias[t * FDIM + wid * 64 + nf * 16 + lr];

    const char* Abase = (const char*)input
        + ((size_t)(base + sr) * (N_NODES * FDIM) + n * FDIM) * 4 + sk * 16;
    const size_t tile_stride = (size_t)BT_TILE * N_NODES * FDIM * 4;

    float4 av0[8], av1[8];
#pragma unroll
    for (int q = 0; q < 8; ++q)
        av0[q] = *reinterpret_cast<const float4*>(Abase + q * 128);
#pragma unroll
    for (int q = 0; q < 8; ++q)
        av1[q] = *reinterpret_cast<const float4*>(Abase + tile_stride + q * 128);

#pragma unroll
    for (int q = 0; q < 8; ++q) {   // cvt tile0 -> sA0
        bf16x4 h; h[0]=(__bf16)av0[q].x; h[1]=(__bf16)av0[q].y;
        h[2]=(__bf16)av0[q].z; h[3]=(__bf16)av0[q].w;
        *reinterpret_cast<bf16x4*>(sA0 + swz(sr * ROW_B + q * 64 + sk * 8, sr)) = h;
    }
    __syncthreads();   // drains W DMA + A(0) writes

    f32x4 acc[2][4];

#define COMPUTE_TILE(SBUF, TI)                                                  \
    {                                                                           \
        _Pragma("unroll")                                                       \
        for (int mf = 0; mf < 2; ++mf)                                          \
            _Pragma("unroll")                                                   \
            for (int nf = 0; nf < 4; ++nf)                                      \
                acc[mf][nf] = f32x4{0.f, 0.f, 0.f, 0.f};                        \
        _Pragma("unroll")                                                       \
        for (int ks = 0; ks < 8; ++ks) {                                        \
            const int kb = ks * 64 + lq * 16;                                   \
            bf16x8 af[2], bfv[4];                                               \
            _Pragma("unroll")                                                   \
            for (int mf = 0; mf < 2; ++mf) {                                    \
                int r = mf * 16 + lr;                                           \
                af[mf] = *reinterpret_cast<const bf16x8*>(                      \
                    SBUF + swz(r * ROW_B + kb, r));                             \
            }                                                                   \
            _Pragma("unroll")                                                   \
            for (int nf = 0; nf < 4; ++nf) {                                    \
                int o = wid * 64 + nf * 16 + lr;                                \
                bfv[nf] = *reinterpret_cast<const bf16x8*>(                     \
                    sWb + swz(o * ROW_B + kb, o));                              \
            }                                                                   \
            _Pragma("unroll")                                                   \
            for (int mf = 0; mf < 2; ++mf)                                      \
                _Pragma("unroll")                                               \
                for (int nf = 0; nf < 4; ++nf)                                  \
                    acc[mf][nf] = __builtin_amdgcn_mfma_f32_16x16x32_bf16(      \
                        af[mf], bfv[nf], acc[mf][nf], 0, 0, 0);                 \
        }                                                                       \
        /* epilogue: +bias, cvt bf16, frag-permuted coalesced store */          \
        _Pragma("unroll")                                                       \
        for (int mf = 0; mf < 2; ++mf)                                          \
            _Pragma("unroll")                                                   \
            for (int j = 0; j < 4; ++j) {                                       \
                bf16x4 h;                                                       \
                _Pragma("unroll")                                               \
                for (int nf = 0; nf < 4; ++nf)                                  \
                    h[nf] = (__bf16)(acc[mf][nf][j] + bv[nf]);                  \
                size_t bt = (size_t)(base + (TI) * BT_TILE + mf * 16 + lq * 4 + j); \
                *reinterpret_cast<bf16x4*>(outb + bt * 32768 + n * 512          \
                                           + wid * 128 + lr * 8) = h;           \
            }                                                                   \
    }

#define CVT_TO(AV, SDST)                                                        \
    {                                                                           \
        _Pragma("unroll")                                                       \
        for (int q = 0; q < 8; ++q) {                                           \
            bf16x4 h; h[0]=(__bf16)AV[q].x; h[1]=(__bf16)AV[q].y;               \
            h[2]=(__bf16)AV[q].z; h[3]=(__bf16)AV[q].w;                         \
            *reinterpret_cast<bf16x4*>(SDST + swz(sr * ROW_B + q * 64 + sk * 8, \
                                                  sr)) = h;                     \
        }                                                                       \
    }

#define LOAD_TILE(AV, TI)                                                       \
    {                                                                           \
        const char* rp = Abase + (size_t)(TI) * tile_stride;                    \
        _Pragma("unroll")                                                       \
        for (int q = 0; q < 8; ++q)                                             \
            AV[q] = *reinterpret_cast<const float4*>(rp + q * 128);             \
    }

    for (int tt = 0; tt < 8; ++tt) {
        const int e = 2 * tt;
        if (e + 2 < TILES) LOAD_TILE(av0, e + 2);
        COMPUTE_TILE(sA0, e);
        CVT_TO(av1, sA1);
        __syncthreads();
        const int od = 2 * tt + 1;
        if (od + 2 < TILES) LOAD_TILE(av1, od + 2);
        COMPUTE_TILE(sA1, od);
        if (tt < 7) {
            CVT_TO(av0, sA0);
            __syncthreads();
        }
    }
#undef COMPUTE_TILE
#undef CVT_TO
#undef LOAD_TILE
}

// ---------------------------------------------------------------------------
// k2: graph aggregation, in-place slot upgrade bf16 -> fp32.
// FINAL EXPERIMENT: 2048 blocks x 2 slots, BOTH slots' gather bursts issued
// back-to-back BEFORE the single barrier -- slot 1's load latency hides
// under slot 0's compute+store phase, halving per-block ramp overhead.
// This is R14's pipelining theory WITHOUT its confound: R14's 512-block
// grid capped co-residency at 2 blocks/CU (grid-size limit -> Occ 20%,
// 1.45 TB/s); 2048 blocks keeps >=5 blocks/CU.
// Per slot: direct 2B permuted gathers (64x2B/wave in a dense 128B window),
// g from LDS (frees s-pipe, R17-neutral), dense 1KB-row fp32 nt stores.
// One vmcnt-draining __syncthreads = in-place fence for both slots.
// ---------------------------------------------------------------------------
__global__ __launch_bounds__(256) void k2_graph_agg(
    char* __restrict__ outb, const float* __restrict__ g)
{
    __shared__ float gs[N_NODES * N_NODES];   // 4 KB
    const int tid = threadIdx.x;
    reinterpret_cast<float4*>(gs)[tid] = reinterpret_cast<const float4*>(g)[tid];

    char* slot0 = outb + (size_t)blockIdx.x * 2 * 32768;
    // p(o) = (o>>6)*64 + (o&15)*4 + ((o>>4)&3); byte offset = p*2, o = tid
    const unsigned pb = ((unsigned)(tid >> 6) << 7) + ((tid & 15u) << 3)
                      + (((tid >> 4) & 3u) << 1);
    const char* s0 = slot0 + pb;
    const char* s1 = slot0 + 32768 + pb;

    // issue BOTH slots' raw gather bursts back-to-back (64 loads in flight)
    unsigned vr0[N_NODES], vr1[N_NODES];
#pragma unroll
    for (int nn = 0; nn < N_NODES; ++nn)
        vr0[nn] = *reinterpret_cast<const unsigned short*>(s0 + nn * 512);
#pragma unroll
    for (int nn = 0; nn < N_NODES; ++nn)
        vr1[nn] = *reinterpret_cast<const unsigned short*>(s1 + nn * 512);
    __syncthreads();   // vmcnt drained: both slots fully read; gs visible

    // ---- slot 0: convert, compute, store ----
    float v[N_NODES];
#pragma unroll
    for (int nn = 0; nn < N_NODES; ++nn) {
        union { unsigned u; float f; } cv; cv.u = vr0[nn] << 16;
        v[nn] = cv.f;
    }
    float* dst0 = (float*)slot0 + tid;
#pragma unroll 4
    for (int m = 0; m < N_NODES; ++m) {
        float s = 0.f;
#pragma unroll
        for (int nn = 0; nn < N_NODES; ++nn)
            s = fmaf(gs[m * N_NODES + nn], v[nn], s);
        __builtin_nontemporal_store(s, dst0 + m * FDIM);
    }

    // ---- slot 1: convert, compute, store ----
#pragma unroll
    for (int nn = 0; nn < N_NODES; ++nn) {
        union { unsigned u; float f; } cv; cv.u = vr1[nn] << 16;
        v[nn] = cv.f;
    }
    float* dst1 = (float*)(slot0 + 32768) + tid;
#pragma unroll 4
    for (int m = 0; m < N_NODES; ++m) {
        float s = 0.f;
#pragma unroll
        for (int nn = 0; nn < N_NODES; ++nn)
            s = fmaf(gs[m * N_NODES + nn], v[nn], s);
        __builtin_nontemporal_store(s, dst1 + m * FDIM);
    }
}

extern "C" void kernel_launch(void* const* d_in, const int* in_sizes, int n_in,
                              void* d_out, int out_size, void* d_ws, size_t ws_size,
                              hipStream_t stream) {
    const float* input  = (const float*)d_in[0];
    const float* g      = (const float*)d_in[1];
    const int*   ntype  = (const int*)d_in[2];
    const float* weight = (const float*)d_in[3];
    const float* bias   = (const float*)d_in[4];
    char* outb = (char*)d_out;
    __bf16* wp = (__bf16*)d_ws;   // 1 MB

    const int BT = in_sizes[0] / (N_NODES * FDIM);   // 4096

    k0_convert_w<<<N_TYPES * FDIM * FDIM / 256, 256, 0, stream>>>(weight, wp);

    // 256 blocks: n = bx>>3 (32), bt-group = bx&7 (8 x 512 rows)
    k1_node_gemm<<<N_NODES * 8, 256, 0, stream>>>(input, wp, bias, ntype, outb);

    // 2048 blocks x 2 slots
    k2_graph_agg<<<BT / 2, 256, 0, stream>>>(outb, g);
}

// Round 21
// 81.115 us; speedup vs baseline: 1.0631x; 1.0631x over previous
//
#include <hip/hip_runtime.h>
#include <hip/hip_bf16.h>
#include <stdint.h>

typedef __bf16 bf16x8 __attribute__((ext_vector_type(8)));
typedef __bf16 bf16x4 __attribute__((ext_vector_type(4)));
typedef float f32x4 __attribute__((ext_vector_type(4)));

#define N_NODES 32
#define FDIM 256
#define N_TYPES 8
#define BT_TILE 32
#define TILES 16              // A-tiles per block
#define ROW_B (FDIM * 2)      // 512 B per LDS row (bf16)

// XOR swizzle: row stride 512B puts each k-column in one bank; (row&7)<<4
// spreads 16B slots across 8 positions. Applied on write and read.
__device__ __forceinline__ unsigned swz(unsigned byte_off, unsigned row) {
    return byte_off ^ ((row & 7u) << 4);
}
__device__ __forceinline__ void lds_dma16(void* lds, const void* g) {
    __builtin_amdgcn_global_load_lds(
        (const __attribute__((address_space(1))) unsigned int*)g,
        (__attribute__((address_space(3))) unsigned int*)lds, 16, 0, 0);
}

// ---------------------------------------------------------------------------
// k0: one-time W fp32->bf16, PRE-SWIZZLED full [256 o x 256 k] image per type
// so k1 stages it with linear global_load_lds. Image byte
// L = (o*512 + k*2) ^ ((o&7)<<4) holds W[t][o][k].  (~3us)
// ---------------------------------------------------------------------------
__global__ __launch_bounds__(256) void k0_convert_w(
    const float* __restrict__ w, __bf16* __restrict__ wp)
{
    int idx = blockIdx.x * 256 + threadIdx.x;   // [t][o][k]
    int t = idx >> 16, o = (idx >> 8) & 255, k = idx & 255;
    unsigned L = (unsigned)(o * ROW_B + k * 2) ^ ((o & 7u) << 4);
    wp[(size_t)t * (FDIM * FDIM) + (L >> 1)] = (__bf16)w[idx];
}

// ---------------------------------------------------------------------------
// k1: persistent-W GEMM (FINAL, ~30us = 6.3+ TB/s on 192 MB traffic -- at
// this structure's BW ceiling). Block = (n, bt-group of 512 rows). Full W[t]
// bf16 resident in LDS (128 KB, DMA'd once via global_load_lds); 16 A-tiles
// [32 x 256], A double-buffered + reg-prefetched one tile ahead;
// XOR-swizzled LDS; bf16 MFMA 16x16x32, fp32 accum; bias in epilogue.
// Writes out1 bf16 into the FIRST 16 KB of each out[bt] 32KB slot,
// MFMA-frag-permuted: element (bt, n, p), p = wid*64 + lr*4 + nf, at byte
// bt*32768 + n*512 + p*2; 8B/lane contiguous stores.
// Session lessons: bf16 epilogue only (all fp32 epilogues = 76-94us, two
// layouts, barrier variants -- mechanism never isolated); never row-major
// scatter (R6: 1.76 TB/s).
// ---------------------------------------------------------------------------
__global__ __launch_bounds__(256, 1) void k1_node_gemm(
    const float* __restrict__ input, const __bf16* __restrict__ wp,
    const float* __restrict__ bias, const int* __restrict__ ntype,
    char* __restrict__ outb)
{
    __shared__ __bf16 sW[FDIM * FDIM];          // 131072 B
    __shared__ __bf16 sA[2][BT_TILE * FDIM];    // 2 x 16384 B  (total = 160 KiB)

    const int tid = threadIdx.x;
    const int n = blockIdx.x >> 3;
    const int base = (blockIdx.x & 7) * (TILES * BT_TILE);
    const int t = ntype[n];

    const int wid = tid >> 6, lane = tid & 63;
    const int lr = lane & 15, lq = lane >> 4;
    const int sr = tid >> 3;        // staging row 0..31
    const int sk = tid & 7;         // staging k-octet

    char* sWb = (char*)sW;
    char* sA0 = (char*)sA[0];
    char* sA1 = (char*)sA[1];

    // ---- prologue ----
    const char* wsrc = (const char*)(wp + (size_t)t * (FDIM * FDIM));
#pragma unroll
    for (int j = 0; j < 32; ++j)
        lds_dma16(sWb + j * 4096 + tid * 16, wsrc + j * 4096 + tid * 16);

    float bv[4];
#pragma unroll
    for (int nf = 0; nf < 4; ++nf)
        bv[nf] = bias[t * FDIM + wid * 64 + nf * 16 + lr];

    const char* Abase = (const char*)input
        + ((size_t)(base + sr) * (N_NODES * FDIM) + n * FDIM) * 4 + sk * 16;
    const size_t tile_stride = (size_t)BT_TILE * N_NODES * FDIM * 4;

    float4 av0[8], av1[8];
#pragma unroll
    for (int q = 0; q < 8; ++q)
        av0[q] = *reinterpret_cast<const float4*>(Abase + q * 128);
#pragma unroll
    for (int q = 0; q < 8; ++q)
        av1[q] = *reinterpret_cast<const float4*>(Abase + tile_stride + q * 128);

#pragma unroll
    for (int q = 0; q < 8; ++q) {   // cvt tile0 -> sA0
        bf16x4 h; h[0]=(__bf16)av0[q].x; h[1]=(__bf16)av0[q].y;
        h[2]=(__bf16)av0[q].z; h[3]=(__bf16)av0[q].w;
        *reinterpret_cast<bf16x4*>(sA0 + swz(sr * ROW_B + q * 64 + sk * 8, sr)) = h;
    }
    __syncthreads();   // drains W DMA + A(0) writes

    f32x4 acc[2][4];

#define COMPUTE_TILE(SBUF, TI)                                                  \
    {                                                                           \
        _Pragma("unroll")                                                       \
        for (int mf = 0; mf < 2; ++mf)                                          \
            _Pragma("unroll")                                                   \
            for (int nf = 0; nf < 4; ++nf)                                      \
                acc[mf][nf] = f32x4{0.f, 0.f, 0.f, 0.f};                        \
        _Pragma("unroll")                                                       \
        for (int ks = 0; ks < 8; ++ks) {                                        \
            const int kb = ks * 64 + lq * 16;                                   \
            bf16x8 af[2], bfv[4];                                               \
            _Pragma("unroll")                                                   \
            for (int mf = 0; mf < 2; ++mf) {                                    \
                int r = mf * 16 + lr;                                           \
                af[mf] = *reinterpret_cast<const bf16x8*>(                      \
                    SBUF + swz(r * ROW_B + kb, r));                             \
            }                                                                   \
            _Pragma("unroll")                                                   \
            for (int nf = 0; nf < 4; ++nf) {                                    \
                int o = wid * 64 + nf * 16 + lr;                                \
                bfv[nf] = *reinterpret_cast<const bf16x8*>(                     \
                    sWb + swz(o * ROW_B + kb, o));                              \
            }                                                                   \
            _Pragma("unroll")                                                   \
            for (int mf = 0; mf < 2; ++mf)                                      \
                _Pragma("unroll")                                               \
                for (int nf = 0; nf < 4; ++nf)                                  \
                    acc[mf][nf] = __builtin_amdgcn_mfma_f32_16x16x32_bf16(      \
                        af[mf], bfv[nf], acc[mf][nf], 0, 0, 0);                 \
        }                                                                       \
        /* epilogue: +bias, cvt bf16, frag-permuted coalesced store */          \
        _Pragma("unroll")                                                       \
        for (int mf = 0; mf < 2; ++mf)                                          \
            _Pragma("unroll")                                                   \
            for (int j = 0; j < 4; ++j) {                                       \
                bf16x4 h;                                                       \
                _Pragma("unroll")                                               \
                for (int nf = 0; nf < 4; ++nf)                                  \
                    h[nf] = (__bf16)(acc[mf][nf][j] + bv[nf]);                  \
                size_t bt = (size_t)(base + (TI) * BT_TILE + mf * 16 + lq * 4 + j); \
                *reinterpret_cast<bf16x4*>(outb + bt * 32768 + n * 512          \
                                           + wid * 128 + lr * 8) = h;           \
            }                                                                   \
    }

#define CVT_TO(AV, SDST)                                                        \
    {                                                                           \
        _Pragma("unroll")                                                       \
        for (int q = 0; q < 8; ++q) {                                           \
            bf16x4 h; h[0]=(__bf16)AV[q].x; h[1]=(__bf16)AV[q].y;               \
            h[2]=(__bf16)AV[q].z; h[3]=(__bf16)AV[q].w;                         \
            *reinterpret_cast<bf16x4*>(SDST + swz(sr * ROW_B + q * 64 + sk * 8, \
                                                  sr)) = h;                     \
        }                                                                       \
    }

#define LOAD_TILE(AV, TI)                                                       \
    {                                                                           \
        const char* rp = Abase + (size_t)(TI) * tile_stride;                    \
        _Pragma("unroll")                                                       \
        for (int q = 0; q < 8; ++q)                                             \
            AV[q] = *reinterpret_cast<const float4*>(rp + q * 128);             \
    }

    for (int tt = 0; tt < 8; ++tt) {
        const int e = 2 * tt;
        if (e + 2 < TILES) LOAD_TILE(av0, e + 2);
        COMPUTE_TILE(sA0, e);
        CVT_TO(av1, sA1);
        __syncthreads();
        const int od = 2 * tt + 1;
        if (od + 2 < TILES) LOAD_TILE(av1, od + 2);
        COMPUTE_TILE(sA1, od);
        if (tt < 7) {
            CVT_TO(av0, sA0);
            __syncthreads();
        }
    }
#undef COMPUTE_TILE
#undef CVT_TO
#undef LOAD_TILE
}

// ---------------------------------------------------------------------------
// k2: graph aggregation, in-place slot upgrade bf16 -> fp32 (FINAL, ~48us).
// Direct 2B permuted gathers (per wave 64x2B covering a dense 128B window);
// g via uniform s_load; one vmcnt-draining __syncthreads = in-place fence;
// dense 1KB-row fp32 stores at o = tid (full lines); nontemporal stores.
// NOTE for future attempts: this kernel's ~2x-over-traffic cost survived
// ten single-variable probes (read grain/mechanism/location, write shape,
// nt, warming, persistent x2, burst-pipeline, g-path x2; R4-R20, all null).
// The fp32-intermediate alternative makes k2 fast (27us) but k1 slow
// (77us, also mechanism-resistant); net worse. 81.4us is the measured
// Pareto point of this decomposition.
// ---------------------------------------------------------------------------
__global__ __launch_bounds__(256) void k2_graph_agg(
    char* __restrict__ outb, const float* __restrict__ g)
{
    const int tid = threadIdx.x;
    char* slot = outb + (size_t)blockIdx.x * 32768;

    const int o = tid;
    // p(o) = (o>>6)*64 + (o&15)*4 + ((o>>4)&3); byte offset = p*2
    const unsigned pb = ((unsigned)(o >> 6) << 7) + ((o & 15u) << 3)
                      + (((o >> 4) & 3u) << 1);
    const char* src = slot + pb;

    float v[N_NODES];
#pragma unroll
    for (int nn = 0; nn < N_NODES; ++nn) {
        unsigned short hv =
            *reinterpret_cast<const unsigned short*>(src + nn * 512);
        union { unsigned u; float f; } cv; cv.u = (unsigned)hv << 16;
        v[nn] = cv.f;
    }
    __syncthreads();   // all block reads done (vmcnt drained) before writes

    float* dst = (float*)slot + o;
#pragma unroll 4
    for (int m = 0; m < N_NODES; ++m) {
        float s = 0.f;
#pragma unroll
        for (int nn = 0; nn < N_NODES; ++nn)
            s = fmaf(g[m * N_NODES + nn], v[nn], s);   // uniform -> s_load
        __builtin_nontemporal_store(s, dst + m * FDIM);
    }
}

extern "C" void kernel_launch(void* const* d_in, const int* in_sizes, int n_in,
                              void* d_out, int out_size, void* d_ws, size_t ws_size,
                              hipStream_t stream) {
    const float* input  = (const float*)d_in[0];
    const float* g      = (const float*)d_in[1];
    const int*   ntype  = (const int*)d_in[2];
    const float* weight = (const float*)d_in[3];
    const float* bias   = (const float*)d_in[4];
    char* outb = (char*)d_out;
    __bf16* wp = (__bf16*)d_ws;   // 1 MB

    const int BT = in_sizes[0] / (N_NODES * FDIM);   // 4096

    k0_convert_w<<<N_TYPES * FDIM * FDIM / 256, 256, 0, stream>>>(weight, wp);

    // 256 blocks: n = bx>>3 (32), bt-group = bx&7 (8 x 512 rows)
    k1_node_gemm<<<N_NODES * 8, 256, 0, stream>>>(input, wp, bias, ntype, outb);

    k2_graph_agg<<<BT, 256, 0, stream>>>(outb, g);
}